// Round 7
// baseline (688.723 us; speedup 1.0000x reference)
//
#include <hip/hip_runtime.h>
#include <cstdint>
#include <cstddef>

// ---------------------------------------------------------------------------
// GAT x2 + LayerNorm on MI355X.
// INTERFACE (established R0-R6): inputs fp32, edge_index int32, OUTPUT fp32.
// Internals h1/out1/h2 bf16 (bandwidth), all arithmetic fp32.
// ---------------------------------------------------------------------------

constexpr int NNODES = 50000;

typedef unsigned short bf16_t;

__device__ __forceinline__ float bf2f(bf16_t b) {
  return __uint_as_float(((unsigned int)b) << 16);
}
__device__ __forceinline__ bf16_t f2bf(float f) {
  unsigned int u = __float_as_uint(f);
  u += 0x7fffu + ((u >> 16) & 1u);   // round to nearest even
  return (bf16_t)(u >> 16);
}
__device__ __forceinline__ float4 bf4_to_f4(ushort4 v) {
  return make_float4(bf2f(v.x), bf2f(v.y), bf2f(v.z), bf2f(v.w));
}
__device__ __forceinline__ ushort4 f4_to_bf4(float4 v) {
  return make_ushort4(f2bf(v.x), f2bf(v.y), f2bf(v.z), f2bf(v.w));
}
__device__ __forceinline__ float lrelu(float x) { return x > 0.f ? x : 0.2f * x; }
__device__ __forceinline__ int clampi(int v, int lo, int hi) {
  return v < lo ? lo : (v > hi ? hi : v);
}
__device__ __forceinline__ int load_edge(const void* ei, int mode, int idx) {
  if (mode) return (int)((const long long*)ei)[idx];
  return ((const int*)ei)[idx];
}

// --------------------------- edge dtype detection --------------------------
__global__ void detect_kernel(const int* __restrict__ ei32, int* __restrict__ mode) {
  __shared__ int nz;
  if (threadIdx.x == 0) nz = 0;
  __syncthreads();
  int idx = 2 * threadIdx.x + 1;     // odd int32 positions, first 512 ints
  if (ei32[idx] != 0) atomicAdd(&nz, 1);
  __syncthreads();
  if (threadIdx.x == 0) mode[0] = (nz == 0) ? 1 : 0;
}

// ------------------------------- CSR build ---------------------------------

__global__ void zero_kernel(int* __restrict__ p, int n) {
  int i = blockIdx.x * blockDim.x + threadIdx.x;
  if (i < n) p[i] = 0;
}

__global__ void hist_kernel(const void* __restrict__ ei, const int* __restrict__ modep,
                            int* __restrict__ counts, int e0, int et) {
  int e = blockIdx.x * blockDim.x + threadIdx.x;
  if (e >= et) return;
  int mode = modep[0];
  int dst = (e < e0) ? load_edge(ei, mode, e0 + e) : (e - e0);  // self loops appended
  dst = clampi(dst, 0, NNODES - 1);
  atomicAdd(&counts[dst], 1);
}

__global__ __launch_bounds__(1024) void scan1_kernel(const int* __restrict__ counts,
                                                     int* __restrict__ rowptr,
                                                     int* __restrict__ bsums) {
  __shared__ int sm[1024];
  int t = threadIdx.x;
  int i = blockIdx.x * 1024 + t;
  sm[t] = (i < NNODES) ? counts[i] : 0;
  __syncthreads();
  for (int off = 1; off < 1024; off <<= 1) {
    int u = (t >= off) ? sm[t - off] : 0;
    __syncthreads();
    sm[t] += u;
    __syncthreads();
  }
  if (i < NNODES) rowptr[i + 1] = sm[t];
  if (t == 1023) bsums[blockIdx.x] = sm[1023];
}

__global__ void scan2_kernel(const int* __restrict__ bsums, int* __restrict__ boff,
                             int nb, int* __restrict__ rowptr, int* __restrict__ cursor) {
  if (threadIdx.x == 0 && blockIdx.x == 0) {
    int run = 0;
    for (int b = 0; b < nb; ++b) { boff[b] = run; run += bsums[b]; }
    rowptr[0] = 0;
    cursor[0] = 0;
  }
}

__global__ __launch_bounds__(1024) void scan3_kernel(const int* __restrict__ boff,
                                                     int* __restrict__ rowptr,
                                                     int* __restrict__ cursor) {
  int i = blockIdx.x * 1024 + threadIdx.x;
  if (i < NNODES) {
    int v = rowptr[i + 1] + boff[blockIdx.x];
    rowptr[i + 1] = v;
    cursor[i + 1] = v;
  }
}

__global__ void fill_kernel(const void* __restrict__ ei, const int* __restrict__ modep,
                            int* __restrict__ cursor, int* __restrict__ col,
                            int e0, int et) {
  int e = blockIdx.x * blockDim.x + threadIdx.x;
  if (e >= et) return;
  int mode = modep[0];
  int src, dst;
  if (e < e0) { src = load_edge(ei, mode, e); dst = load_edge(ei, mode, e0 + e); }
  else        { src = dst = e - e0; }
  src = clampi(src, 0, NNODES - 1);
  dst = clampi(dst, 0, NNODES - 1);
  int pos = atomicAdd(&cursor[dst], 1);
  col[pos] = src;
}

// --------------------------------- GEMM ------------------------------------
// C[M,NC] = A[M,K] @ B[K,NC].  B fp32; A bf16 or fp32; C bf16 (internal).
// 64x64 tile, 256 threads, 4x4 micro-tile, BK=16.

template <int K, int NC, bool A_BF16>
__global__ __launch_bounds__(256) void gemm_kernel(const void* __restrict__ Av,
                                                   const float* __restrict__ B,
                                                   bf16_t* __restrict__ C, int M) {
  __shared__ float As[16][64];   // [k][m]
  __shared__ float Bs[16][64];   // [k][n]
  const int t  = threadIdx.x;
  const int tx = t & 15, ty = t >> 4;
  const int bm = blockIdx.x * 64, bn = blockIdx.y * 64;
  const int ar = t >> 2, ak = (t & 3) << 2;       // A: 64 rows x 16 k
  const int br = t >> 4, bc = (t & 15) << 2;      // B: 16 k x 64 cols
  float c[4][4] = {};
  for (int k0 = 0; k0 < K; k0 += 16) {
    float4 av = make_float4(0.f, 0.f, 0.f, 0.f);
    int arow = bm + ar;
    if (arow < M) {
      if constexpr (A_BF16) {
        ushort4 v = *(const ushort4*)((const bf16_t*)Av + (size_t)arow * K + k0 + ak);
        av = bf4_to_f4(v);
      } else {
        av = *(const float4*)((const float*)Av + (size_t)arow * K + k0 + ak);
      }
    }
    As[ak + 0][ar] = av.x; As[ak + 1][ar] = av.y;
    As[ak + 2][ar] = av.z; As[ak + 3][ar] = av.w;
    *(float4*)(&Bs[br][bc]) = *(const float4*)(B + (size_t)(k0 + br) * NC + bn + bc);
    __syncthreads();
#pragma unroll
    for (int kk = 0; kk < 16; ++kk) {
      float4 a = *(const float4*)(&As[kk][ty << 2]);
      float4 b = *(const float4*)(&Bs[kk][tx << 2]);
      c[0][0] += a.x * b.x; c[0][1] += a.x * b.y; c[0][2] += a.x * b.z; c[0][3] += a.x * b.w;
      c[1][0] += a.y * b.x; c[1][1] += a.y * b.y; c[1][2] += a.y * b.z; c[1][3] += a.y * b.w;
      c[2][0] += a.z * b.x; c[2][1] += a.z * b.y; c[2][2] += a.z * b.z; c[2][3] += a.z * b.w;
      c[3][0] += a.w * b.x; c[3][1] += a.w * b.y; c[3][2] += a.w * b.z; c[3][3] += a.w * b.w;
    }
    __syncthreads();
  }
#pragma unroll
  for (int i = 0; i < 4; ++i) {
    int row = bm + (ty << 2) + i;
    if (row < M) {
      ushort4 o = f4_to_bf4(make_float4(c[i][0], c[i][1], c[i][2], c[i][3]));
      *(ushort4*)(C + (size_t)row * NC + bn + (tx << 2)) = o;
    }
  }
}

// ------------------------------ attention scores ---------------------------
// layer1: F = 256 = [H=4][C=64]; 4 channels/lane; head = lane>>4
__global__ __launch_bounds__(256) void scores1_kernel(const bf16_t* __restrict__ h,
                                                      const float* __restrict__ asrc,
                                                      const float* __restrict__ adst,
                                                      float* __restrict__ es,
                                                      float* __restrict__ ed) {
  int node = (blockIdx.x * blockDim.x + threadIdx.x) >> 6;
  if (node >= NNODES) return;
  int lane = threadIdx.x & 63;
  float4 hv = bf4_to_f4(*(const ushort4*)(h + (size_t)node * 256 + 4 * lane));
  float4 av = *(const float4*)(asrc + 4 * lane);
  float4 dv = *(const float4*)(adst + 4 * lane);
  float ps = hv.x * av.x + hv.y * av.y + hv.z * av.z + hv.w * av.w;
  float pd = hv.x * dv.x + hv.y * dv.y + hv.z * dv.z + hv.w * dv.w;
  for (int m = 1; m < 16; m <<= 1) { ps += __shfl_xor(ps, m); pd += __shfl_xor(pd, m); }
  if ((lane & 15) == 0) {
    es[node * 4 + (lane >> 4)] = ps;
    ed[node * 4 + (lane >> 4)] = pd;
  }
}

// layer2: F = 512 = [H=4][C=128]; two chunks/lane; heads (lane>>5) and +2
__global__ __launch_bounds__(256) void scores2_kernel(const bf16_t* __restrict__ h,
                                                      const float* __restrict__ asrc,
                                                      const float* __restrict__ adst,
                                                      float* __restrict__ es,
                                                      float* __restrict__ ed) {
  int node = (blockIdx.x * blockDim.x + threadIdx.x) >> 6;
  if (node >= NNODES) return;
  int lane = threadIdx.x & 63;
  float4 hA = bf4_to_f4(*(const ushort4*)(h + (size_t)node * 512 + 4 * lane));
  float4 hB = bf4_to_f4(*(const ushort4*)(h + (size_t)node * 512 + 4 * lane + 256));
  float4 aA = *(const float4*)(asrc + 4 * lane);
  float4 aB = *(const float4*)(asrc + 4 * lane + 256);
  float4 dA = *(const float4*)(adst + 4 * lane);
  float4 dB = *(const float4*)(adst + 4 * lane + 256);
  float psA = hA.x * aA.x + hA.y * aA.y + hA.z * aA.z + hA.w * aA.w;
  float psB = hB.x * aB.x + hB.y * aB.y + hB.z * aB.z + hB.w * aB.w;
  float pdA = hA.x * dA.x + hA.y * dA.y + hA.z * dA.z + hA.w * dA.w;
  float pdB = hB.x * dB.x + hB.y * dB.y + hB.z * dB.z + hB.w * dB.w;
  for (int m = 1; m < 32; m <<= 1) {
    psA += __shfl_xor(psA, m); psB += __shfl_xor(psB, m);
    pdA += __shfl_xor(pdA, m); pdB += __shfl_xor(pdB, m);
  }
  if ((lane & 31) == 0) {
    int g = lane >> 5;
    es[node * 4 + g]     = psA;  es[node * 4 + g + 2] = psB;
    ed[node * 4 + g]     = pdA;  ed[node * 4 + g + 2] = pdB;
  }
}

// ------------------------------- aggregation -------------------------------
// layer 1: wave per node; lane holds 4 channels at 4*lane (head = lane>>4).
__global__ __launch_bounds__(256) void aggregate1_kernel(
    const bf16_t* __restrict__ h, const float* __restrict__ es,
    const float* __restrict__ ed, const int* __restrict__ rowptr,
    const int* __restrict__ col, const float* __restrict__ b1,
    bf16_t* __restrict__ out) {
  int node = (blockIdx.x * blockDim.x + threadIdx.x) >> 6;
  if (node >= NNODES) return;
  int lane = threadIdx.x & 63;
  int head = lane >> 4;
  float edv = ed[node * 4 + head];
  int beg = rowptr[node], end = rowptr[node + 1];
  const ushort4* hb = (const ushort4*)h;   // row = 64 ushort4
  float4 acc = make_float4(0.f, 0.f, 0.f, 0.f);
  float m = -__builtin_inff(), l = 0.f;
  for (int j = beg; j < end; ++j) {
    int s = col[j];
    float e = lrelu(es[s * 4 + head] + edv);
    float4 hv = bf4_to_f4(hb[(size_t)s * 64 + lane]);
    float nm = fmaxf(m, e);
    float sc = __expf(m - nm);
    float p  = __expf(e - nm);
    l = l * sc + p;
    acc.x = acc.x * sc + p * hv.x;
    acc.y = acc.y * sc + p * hv.y;
    acc.z = acc.z * sc + p * hv.z;
    acc.w = acc.w * sc + p * hv.w;
    m = nm;
  }
  float inv = 1.f / (l + 1e-16f);
  float4 bb = *(const float4*)(b1 + 4 * lane);
  float4 o;
  o.x = fmaxf(acc.x * inv + bb.x, 0.f);
  o.y = fmaxf(acc.y * inv + bb.y, 0.f);
  o.z = fmaxf(acc.z * inv + bb.z, 0.f);
  o.w = fmaxf(acc.w * inv + bb.w, 0.f);
  *(ushort4*)(out + (size_t)node * 256 + 4 * lane) = f4_to_bf4(o);
}

// layer 2: wave per node; lane holds chunks at 4*lane (head hA=lane>>5) and
// 4*lane+256 (head hB=hA+2). Epilogue: head mean (shfl xor 32 adds the other
// two heads), +b2, LayerNorm over 128, fp32 store.
__global__ __launch_bounds__(256) void aggregate2_ln_kernel(
    const bf16_t* __restrict__ h, const float* __restrict__ es,
    const float* __restrict__ ed, const int* __restrict__ rowptr,
    const int* __restrict__ col, const float* __restrict__ b2,
    const float* __restrict__ gamma, const float* __restrict__ beta,
    float* __restrict__ out) {
  int node = (blockIdx.x * blockDim.x + threadIdx.x) >> 6;
  if (node >= NNODES) return;
  int lane = threadIdx.x & 63;
  int hA = lane >> 5, hB = hA + 2;
  float edA = ed[node * 4 + hA], edB = ed[node * 4 + hB];
  int beg = rowptr[node], end = rowptr[node + 1];
  const ushort4* hb = (const ushort4*)h;   // row = 128 ushort4
  float4 accA = make_float4(0.f, 0.f, 0.f, 0.f);
  float4 accB = make_float4(0.f, 0.f, 0.f, 0.f);
  float mA = -__builtin_inff(), lA = 0.f;
  float mB = -__builtin_inff(), lB = 0.f;
  for (int j = beg; j < end; ++j) {
    int s = col[j];
    float eA = lrelu(es[s * 4 + hA] + edA);
    float eB = lrelu(es[s * 4 + hB] + edB);
    float4 vA = bf4_to_f4(hb[(size_t)s * 128 + lane]);
    float4 vB = bf4_to_f4(hb[(size_t)s * 128 + lane + 64]);
    float nmA = fmaxf(mA, eA);
    float scA = __expf(mA - nmA);
    float pA  = __expf(eA - nmA);
    lA = lA * scA + pA;
    accA.x = accA.x * scA + pA * vA.x;
    accA.y = accA.y * scA + pA * vA.y;
    accA.z = accA.z * scA + pA * vA.z;
    accA.w = accA.w * scA + pA * vA.w;
    mA = nmA;
    float nmB = fmaxf(mB, eB);
    float scB = __expf(mB - nmB);
    float pB  = __expf(eB - nmB);
    lB = lB * scB + pB;
    accB.x = accB.x * scB + pB * vB.x;
    accB.y = accB.y * scB + pB * vB.y;
    accB.z = accB.z * scB + pB * vB.z;
    accB.w = accB.w * scB + pB * vB.w;
    mB = nmB;
  }
  float invA = 1.f / (lA + 1e-16f), invB = 1.f / (lB + 1e-16f);
  float4 s4;
  s4.x = accA.x * invA + accB.x * invB;
  s4.y = accA.y * invA + accB.y * invB;
  s4.z = accA.z * invA + accB.z * invB;
  s4.w = accA.w * invA + accB.w * invB;
  // add other two heads (lane ^ 32 holds same channels, heads {1-hA, 3-hA})
  s4.x += __shfl_xor(s4.x, 32);
  s4.y += __shfl_xor(s4.y, 32);
  s4.z += __shfl_xor(s4.z, 32);
  s4.w += __shfl_xor(s4.w, 32);
  int c0 = (4 * lane) & 127;
  float4 b2v = *(const float4*)(b2 + c0);
  s4.x = s4.x * 0.25f + b2v.x;
  s4.y = s4.y * 0.25f + b2v.y;
  s4.z = s4.z * 0.25f + b2v.z;
  s4.w = s4.w * 0.25f + b2v.w;
  // LayerNorm over 128 (values duplicated between half-waves; reduce 32 lanes)
  float part = s4.x + s4.y + s4.z + s4.w;
  for (int m = 1; m < 32; m <<= 1) part += __shfl_xor(part, m);
  float mu = part * (1.f / 128.f);
  float dx = s4.x - mu, dy = s4.y - mu, dz = s4.z - mu, dw = s4.w - mu;
  float sq = dx * dx + dy * dy + dz * dz + dw * dw;
  for (int m = 1; m < 32; m <<= 1) sq += __shfl_xor(sq, m);
  float r = rsqrtf(sq * (1.f / 128.f) + 1e-5f);
  float4 g = *(const float4*)(gamma + c0);
  float4 bt = *(const float4*)(beta + c0);
  if (lane < 32) {
    float4 o;
    o.x = dx * r * g.x + bt.x;
    o.y = dy * r * g.y + bt.y;
    o.z = dz * r * g.z + bt.z;
    o.w = dw * r * g.w + bt.w;
    *(float4*)(out + (size_t)node * 128 + c0) = o;   // FP32 output
  }
}

// ------------------------------- launcher ----------------------------------

extern "C" void kernel_launch(void* const* d_in, const int* in_sizes, int n_in,
                              void* d_out, int out_size, void* d_ws, size_t ws_size,
                              hipStream_t stream) {
  const float* x     = (const float*)d_in[0];
  const void*  ei    = d_in[1];            // int32 (detect keeps int64 fallback)
  const float* W1    = (const float*)d_in[2];
  const float* asrc1 = (const float*)d_in[3];
  const float* adst1 = (const float*)d_in[4];
  const float* b1    = (const float*)d_in[5];
  const float* W2    = (const float*)d_in[6];
  const float* asrc2 = (const float*)d_in[7];
  const float* adst2 = (const float*)d_in[8];
  const float* b2    = (const float*)d_in[9];
  const float* gamma = (const float*)d_in[10];
  const float* beta  = (const float*)d_in[11];
  float* out = (float*)d_out;              // FP32 output (established R5)

  const int E0 = in_sizes[1] / 2;       // 800000 raw edges
  const int ET = E0 + NNODES;           // + self loops

  // workspace layout (~84 MB, proven safe); h1 overlays h2's tail.
  char* w = (char*)d_ws;
  bf16_t* out1 = (bf16_t*)(w + 0);            // 25.6 MB   [aggregate1..gemm2]
  bf16_t* h2   = (bf16_t*)(w + 25600000);     // 51.2 MB   [gemm2..]
  bf16_t* h1   = (bf16_t*)(w + 51200000);     // 25.6 MB   [gemm1..aggregate1]
  float* es1  = (float*)(w + 76800000);       // 800 KB each
  float* ed1  = (float*)(w + 77600000);
  float* es2  = (float*)(w + 78400000);
  float* ed2  = (float*)(w + 79200000);
  int* rowptr = (int*)(w + 80000000);         // (N+1)*4
  int* cursor = (int*)(w + 80200064);
  int* counts = (int*)(w + 80400128);
  int* col    = (int*)(w + 80600192);         // ET*4 = 3.4 MB
  int* bsums  = (int*)(w + 84000192);
  int* boff   = (int*)(w + 84000448);
  int* mode   = (int*)(w + 84000704);

  const int NB = (NNODES + 1023) / 1024;   // 49

  // ---- edge dtype detect + CSR build ----
  detect_kernel<<<1, 256, 0, stream>>>((const int*)ei, mode);
  zero_kernel<<<(NNODES + 255) / 256, 256, 0, stream>>>(counts, NNODES);
  hist_kernel<<<(ET + 255) / 256, 256, 0, stream>>>(ei, mode, counts, E0, ET);
  scan1_kernel<<<NB, 1024, 0, stream>>>(counts, rowptr, bsums);
  scan2_kernel<<<1, 64, 0, stream>>>(bsums, boff, NB, rowptr, cursor);
  scan3_kernel<<<NB, 1024, 0, stream>>>(boff, rowptr, cursor);
  fill_kernel<<<(ET + 255) / 256, 256, 0, stream>>>(ei, mode, cursor, col, E0, ET);

  const int MB = (NNODES + 63) / 64;       // 782
  const int NODE_BLOCKS = (NNODES + 3) / 4;

  // ---- layer 1 ----
  gemm_kernel<128, 256, false><<<dim3(MB, 4), 256, 0, stream>>>(x, W1, h1, NNODES);
  scores1_kernel<<<NODE_BLOCKS, 256, 0, stream>>>(h1, asrc1, adst1, es1, ed1);
  aggregate1_kernel<<<NODE_BLOCKS, 256, 0, stream>>>(h1, es1, ed1, rowptr, col, b1, out1);

  // ---- layer 2 ----
  gemm_kernel<256, 512, true><<<dim3(MB, 8), 256, 0, stream>>>(out1, W2, h2, NNODES);
  scores2_kernel<<<NODE_BLOCKS, 256, 0, stream>>>(h2, asrc2, adst2, es2, ed2);
  aggregate2_ln_kernel<<<NODE_BLOCKS, 256, 0, stream>>>(h2, es2, ed2, rowptr, col,
                                                        b2, gamma, beta, out);
}

// Round 8
// 547.739 us; speedup vs baseline: 1.2574x; 1.2574x over previous
//
#include <hip/hip_runtime.h>
#include <cstdint>
#include <cstddef>

// ---------------------------------------------------------------------------
// GAT x2 + LayerNorm on MI355X.
// Interface (established R0-R7): inputs fp32, edge_index int32, output fp32.
// R8: MFMA bf16 GEMMs (16x16x32), one-time x/W -> bf16 prep kernels.
// ---------------------------------------------------------------------------

constexpr int NNODES = 50000;

typedef unsigned short bf16_t;
typedef __attribute__((ext_vector_type(8))) short bf16x8;
typedef __attribute__((ext_vector_type(4))) float f32x4;

__device__ __forceinline__ float bf2f(bf16_t b) {
  return __uint_as_float(((unsigned int)b) << 16);
}
__device__ __forceinline__ bf16_t f2bf(float f) {
  unsigned int u = __float_as_uint(f);
  u += 0x7fffu + ((u >> 16) & 1u);   // round to nearest even
  return (bf16_t)(u >> 16);
}
__device__ __forceinline__ float4 bf4_to_f4(ushort4 v) {
  return make_float4(bf2f(v.x), bf2f(v.y), bf2f(v.z), bf2f(v.w));
}
__device__ __forceinline__ ushort4 f4_to_bf4(float4 v) {
  return make_ushort4(f2bf(v.x), f2bf(v.y), f2bf(v.z), f2bf(v.w));
}
__device__ __forceinline__ float lrelu(float x) { return x > 0.f ? x : 0.2f * x; }
__device__ __forceinline__ int clampi(int v, int lo, int hi) {
  return v < lo ? lo : (v > hi ? hi : v);
}
__device__ __forceinline__ int load_edge(const void* ei, int mode, int idx) {
  if (mode) return (int)((const long long*)ei)[idx];
  return ((const int*)ei)[idx];
}

// ------------------------------ prep kernels -------------------------------

__global__ void convert_x_kernel(const float* __restrict__ x, bf16_t* __restrict__ xb,
                                 int n4) {
  int i = blockIdx.x * blockDim.x + threadIdx.x;
  if (i >= n4) return;
  float4 v = *(const float4*)(x + 4 * (size_t)i);
  *(ushort4*)(xb + 4 * (size_t)i) = f4_to_bf4(v);
}

// Wt[n][k] = bf16(W[k][n]);  grid = NC blocks, block = K threads
template <int K, int NC>
__global__ void transpose_w_kernel(const float* __restrict__ W, bf16_t* __restrict__ Wt) {
  int n = blockIdx.x;
  int k = threadIdx.x;
  Wt[(size_t)n * K + k] = f2bf(W[(size_t)k * NC + n]);
}

// --------------------------- edge dtype detection --------------------------
__global__ void detect_kernel(const int* __restrict__ ei32, int* __restrict__ mode) {
  __shared__ int nz;
  if (threadIdx.x == 0) nz = 0;
  __syncthreads();
  int idx = 2 * threadIdx.x + 1;
  if (ei32[idx] != 0) atomicAdd(&nz, 1);
  __syncthreads();
  if (threadIdx.x == 0) mode[0] = (nz == 0) ? 1 : 0;
}

// ------------------------------- CSR build ---------------------------------

__global__ void zero_kernel(int* __restrict__ p, int n) {
  int i = blockIdx.x * blockDim.x + threadIdx.x;
  if (i < n) p[i] = 0;
}

__global__ void hist_kernel(const void* __restrict__ ei, const int* __restrict__ modep,
                            int* __restrict__ counts, int e0, int et) {
  int e = blockIdx.x * blockDim.x + threadIdx.x;
  if (e >= et) return;
  int mode = modep[0];
  int dst = (e < e0) ? load_edge(ei, mode, e0 + e) : (e - e0);
  dst = clampi(dst, 0, NNODES - 1);
  atomicAdd(&counts[dst], 1);
}

__global__ __launch_bounds__(1024) void scan1_kernel(const int* __restrict__ counts,
                                                     int* __restrict__ rowptr,
                                                     int* __restrict__ bsums) {
  __shared__ int sm[1024];
  int t = threadIdx.x;
  int i = blockIdx.x * 1024 + t;
  sm[t] = (i < NNODES) ? counts[i] : 0;
  __syncthreads();
  for (int off = 1; off < 1024; off <<= 1) {
    int u = (t >= off) ? sm[t - off] : 0;
    __syncthreads();
    sm[t] += u;
    __syncthreads();
  }
  if (i < NNODES) rowptr[i + 1] = sm[t];
  if (t == 1023) bsums[blockIdx.x] = sm[1023];
}

__global__ void scan2_kernel(const int* __restrict__ bsums, int* __restrict__ boff,
                             int nb, int* __restrict__ rowptr, int* __restrict__ cursor) {
  if (threadIdx.x == 0 && blockIdx.x == 0) {
    int run = 0;
    for (int b = 0; b < nb; ++b) { boff[b] = run; run += bsums[b]; }
    rowptr[0] = 0;
    cursor[0] = 0;
  }
}

__global__ __launch_bounds__(1024) void scan3_kernel(const int* __restrict__ boff,
                                                     int* __restrict__ rowptr,
                                                     int* __restrict__ cursor) {
  int i = blockIdx.x * 1024 + threadIdx.x;
  if (i < NNODES) {
    int v = rowptr[i + 1] + boff[blockIdx.x];
    rowptr[i + 1] = v;
    cursor[i + 1] = v;
  }
}

__global__ void fill_kernel(const void* __restrict__ ei, const int* __restrict__ modep,
                            int* __restrict__ cursor, int* __restrict__ col,
                            int e0, int et) {
  int e = blockIdx.x * blockDim.x + threadIdx.x;
  if (e >= et) return;
  int mode = modep[0];
  int src, dst;
  if (e < e0) { src = load_edge(ei, mode, e); dst = load_edge(ei, mode, e0 + e); }
  else        { src = dst = e - e0; }
  src = clampi(src, 0, NNODES - 1);
  dst = clampi(dst, 0, NNODES - 1);
  int pos = atomicAdd(&cursor[dst], 1);
  col[pos] = src;
}

// ------------------------------ MFMA GEMM ----------------------------------
// C[M,NC] = A[M,K] @ W[K,NC], with A bf16 [M][K] k-major and
// Wt bf16 [NC][K] k-major. C bf16. Tile 64x64, BK=32, 4 waves.
// mfma_f32_16x16x32_bf16 fragment maps (verified, learn_hip m89/m120):
//   A: m = lane&15, k = (lane>>4)*8 + j     (8 halves, ds_read_b128)
//   B: n = lane&15, k = (lane>>4)*8 + j
//   D: col = lane&15, row = (lane>>4)*4 + reg
// LDS row stride 40 halves (80 B): b128 access starts cover all 32 banks.

template <int K, int NC>
__global__ __launch_bounds__(256) void gemm_mfma_kernel(const bf16_t* __restrict__ A,
                                                        const bf16_t* __restrict__ Wt,
                                                        bf16_t* __restrict__ C, int M) {
  __shared__ __align__(16) ushort As[64 * 40];
  __shared__ __align__(16) ushort Bs[64 * 40];
  const int t    = threadIdx.x;
  const int wv   = t >> 6;
  const int lane = t & 63;
  const int m    = lane & 15;
  const int quad = lane >> 4;
  const int bm = blockIdx.x * 64, bn = blockIdx.y * 64;

  const int srow = t & 63;        // staging row
  const int sk8  = t >> 6;        // staging 8-half chunk (0..3)

  f32x4 acc0 = {0.f, 0.f, 0.f, 0.f};
  f32x4 acc1 = {0.f, 0.f, 0.f, 0.f};
  f32x4 acc2 = {0.f, 0.f, 0.f, 0.f};
  f32x4 acc3 = {0.f, 0.f, 0.f, 0.f};

  for (int k0 = 0; k0 < K; k0 += 32) {
    // stage A (clamped rows) and Wt tiles: 16B per thread each
    int ga = clampi(bm + srow, 0, M - 1);
    float4 av = *(const float4*)(A + (size_t)ga * K + k0 + sk8 * 8);
    *(float4*)(&As[srow * 40 + sk8 * 8]) = av;
    float4 bv = *(const float4*)(Wt + (size_t)(bn + srow) * K + k0 + sk8 * 8);
    *(float4*)(&Bs[srow * 40 + sk8 * 8]) = bv;
    __syncthreads();

    bf16x8 af = *(const bf16x8*)(&As[(wv * 16 + m) * 40 + quad * 8]);
    bf16x8 b0 = *(const bf16x8*)(&Bs[(0 * 16 + m) * 40 + quad * 8]);
    bf16x8 b1 = *(const bf16x8*)(&Bs[(1 * 16 + m) * 40 + quad * 8]);
    bf16x8 b2 = *(const bf16x8*)(&Bs[(2 * 16 + m) * 40 + quad * 8]);
    bf16x8 b3 = *(const bf16x8*)(&Bs[(3 * 16 + m) * 40 + quad * 8]);
    acc0 = __builtin_amdgcn_mfma_f32_16x16x32_bf16(af, b0, acc0, 0, 0, 0);
    acc1 = __builtin_amdgcn_mfma_f32_16x16x32_bf16(af, b1, acc1, 0, 0, 0);
    acc2 = __builtin_amdgcn_mfma_f32_16x16x32_bf16(af, b2, acc2, 0, 0, 0);
    acc3 = __builtin_amdgcn_mfma_f32_16x16x32_bf16(af, b3, acc3, 0, 0, 0);
    __syncthreads();
  }

  // epilogue: D row = quad*4 + r, col = lane&15
#pragma unroll
  for (int r = 0; r < 4; ++r) {
    int row = bm + wv * 16 + quad * 4 + r;
    if (row < M) {
      size_t base = (size_t)row * NC + bn;
      C[base +  0 + m] = f2bf(acc0[r]);
      C[base + 16 + m] = f2bf(acc1[r]);
      C[base + 32 + m] = f2bf(acc2[r]);
      C[base + 48 + m] = f2bf(acc3[r]);
    }
  }
}

// ------------------------------ attention scores ---------------------------
// layer1: F = 256 = [H=4][C=64]; 4 channels/lane; head = lane>>4
__global__ __launch_bounds__(256) void scores1_kernel(const bf16_t* __restrict__ h,
                                                      const float* __restrict__ asrc,
                                                      const float* __restrict__ adst,
                                                      float* __restrict__ es,
                                                      float* __restrict__ ed) {
  int node = (blockIdx.x * blockDim.x + threadIdx.x) >> 6;
  if (node >= NNODES) return;
  int lane = threadIdx.x & 63;
  float4 hv = bf4_to_f4(*(const ushort4*)(h + (size_t)node * 256 + 4 * lane));
  float4 av = *(const float4*)(asrc + 4 * lane);
  float4 dv = *(const float4*)(adst + 4 * lane);
  float ps = hv.x * av.x + hv.y * av.y + hv.z * av.z + hv.w * av.w;
  float pd = hv.x * dv.x + hv.y * dv.y + hv.z * dv.z + hv.w * dv.w;
  for (int m = 1; m < 16; m <<= 1) { ps += __shfl_xor(ps, m); pd += __shfl_xor(pd, m); }
  if ((lane & 15) == 0) {
    es[node * 4 + (lane >> 4)] = ps;
    ed[node * 4 + (lane >> 4)] = pd;
  }
}

// layer2: F = 512 = [H=4][C=128]; two chunks/lane; heads (lane>>5) and +2
__global__ __launch_bounds__(256) void scores2_kernel(const bf16_t* __restrict__ h,
                                                      const float* __restrict__ asrc,
                                                      const float* __restrict__ adst,
                                                      float* __restrict__ es,
                                                      float* __restrict__ ed) {
  int node = (blockIdx.x * blockDim.x + threadIdx.x) >> 6;
  if (node >= NNODES) return;
  int lane = threadIdx.x & 63;
  float4 hA = bf4_to_f4(*(const ushort4*)(h + (size_t)node * 512 + 4 * lane));
  float4 hB = bf4_to_f4(*(const ushort4*)(h + (size_t)node * 512 + 4 * lane + 256));
  float4 aA = *(const float4*)(asrc + 4 * lane);
  float4 aB = *(const float4*)(asrc + 4 * lane + 256);
  float4 dA = *(const float4*)(adst + 4 * lane);
  float4 dB = *(const float4*)(adst + 4 * lane + 256);
  float psA = hA.x * aA.x + hA.y * aA.y + hA.z * aA.z + hA.w * aA.w;
  float psB = hB.x * aB.x + hB.y * aB.y + hB.z * aB.z + hB.w * aB.w;
  float pdA = hA.x * dA.x + hA.y * dA.y + hA.z * dA.z + hA.w * dA.w;
  float pdB = hB.x * dB.x + hB.y * dB.y + hB.z * dB.z + hB.w * dB.w;
  for (int m = 1; m < 32; m <<= 1) {
    psA += __shfl_xor(psA, m); psB += __shfl_xor(psB, m);
    pdA += __shfl_xor(pdA, m); pdB += __shfl_xor(pdB, m);
  }
  if ((lane & 31) == 0) {
    int g = lane >> 5;
    es[node * 4 + g]     = psA;  es[node * 4 + g + 2] = psB;
    ed[node * 4 + g]     = pdA;  ed[node * 4 + g + 2] = pdB;
  }
}

// ------------------------------- aggregation -------------------------------
// layer 1: wave per node; lane holds 4 channels at 4*lane (head = lane>>4).
__global__ __launch_bounds__(256) void aggregate1_kernel(
    const bf16_t* __restrict__ h, const float* __restrict__ es,
    const float* __restrict__ ed, const int* __restrict__ rowptr,
    const int* __restrict__ col, const float* __restrict__ b1,
    bf16_t* __restrict__ out) {
  int node = (blockIdx.x * blockDim.x + threadIdx.x) >> 6;
  if (node >= NNODES) return;
  int lane = threadIdx.x & 63;
  int head = lane >> 4;
  float edv = ed[node * 4 + head];
  int beg = rowptr[node], end = rowptr[node + 1];
  const ushort4* hb = (const ushort4*)h;   // row = 64 ushort4
  float4 acc = make_float4(0.f, 0.f, 0.f, 0.f);
  float m = -__builtin_inff(), l = 0.f;
  for (int j = beg; j < end; ++j) {
    int s = col[j];
    float e = lrelu(es[s * 4 + head] + edv);
    float4 hv = bf4_to_f4(hb[(size_t)s * 64 + lane]);
    float nm = fmaxf(m, e);
    float sc = __expf(m - nm);
    float p  = __expf(e - nm);
    l = l * sc + p;
    acc.x = acc.x * sc + p * hv.x;
    acc.y = acc.y * sc + p * hv.y;
    acc.z = acc.z * sc + p * hv.z;
    acc.w = acc.w * sc + p * hv.w;
    m = nm;
  }
  float inv = 1.f / (l + 1e-16f);
  float4 bb = *(const float4*)(b1 + 4 * lane);
  float4 o;
  o.x = fmaxf(acc.x * inv + bb.x, 0.f);
  o.y = fmaxf(acc.y * inv + bb.y, 0.f);
  o.z = fmaxf(acc.z * inv + bb.z, 0.f);
  o.w = fmaxf(acc.w * inv + bb.w, 0.f);
  *(ushort4*)(out + (size_t)node * 256 + 4 * lane) = f4_to_bf4(o);
}

// layer 2: wave per node; epilogue head-mean + b2 + LayerNorm -> fp32 out.
__global__ __launch_bounds__(256) void aggregate2_ln_kernel(
    const bf16_t* __restrict__ h, const float* __restrict__ es,
    const float* __restrict__ ed, const int* __restrict__ rowptr,
    const int* __restrict__ col, const float* __restrict__ b2,
    const float* __restrict__ gamma, const float* __restrict__ beta,
    float* __restrict__ out) {
  int node = (blockIdx.x * blockDim.x + threadIdx.x) >> 6;
  if (node >= NNODES) return;
  int lane = threadIdx.x & 63;
  int hA = lane >> 5, hB = hA + 2;
  float edA = ed[node * 4 + hA], edB = ed[node * 4 + hB];
  int beg = rowptr[node], end = rowptr[node + 1];
  const ushort4* hb = (const ushort4*)h;   // row = 128 ushort4
  float4 accA = make_float4(0.f, 0.f, 0.f, 0.f);
  float4 accB = make_float4(0.f, 0.f, 0.f, 0.f);
  float mA = -__builtin_inff(), lA = 0.f;
  float mB = -__builtin_inff(), lB = 0.f;
  for (int j = beg; j < end; ++j) {
    int s = col[j];
    float eA = lrelu(es[s * 4 + hA] + edA);
    float eB = lrelu(es[s * 4 + hB] + edB);
    float4 vA = bf4_to_f4(hb[(size_t)s * 128 + lane]);
    float4 vB = bf4_to_f4(hb[(size_t)s * 128 + lane + 64]);
    float nmA = fmaxf(mA, eA);
    float scA = __expf(mA - nmA);
    float pA  = __expf(eA - nmA);
    lA = lA * scA + pA;
    accA.x = accA.x * scA + pA * vA.x;
    accA.y = accA.y * scA + pA * vA.y;
    accA.z = accA.z * scA + pA * vA.z;
    accA.w = accA.w * scA + pA * vA.w;
    mA = nmA;
    float nmB = fmaxf(mB, eB);
    float scB = __expf(mB - nmB);
    float pB  = __expf(eB - nmB);
    lB = lB * scB + pB;
    accB.x = accB.x * scB + pB * vB.x;
    accB.y = accB.y * scB + pB * vB.y;
    accB.z = accB.z * scB + pB * vB.z;
    accB.w = accB.w * scB + pB * vB.w;
    mB = nmB;
  }
  float invA = 1.f / (lA + 1e-16f), invB = 1.f / (lB + 1e-16f);
  float4 s4;
  s4.x = accA.x * invA + accB.x * invB;
  s4.y = accA.y * invA + accB.y * invB;
  s4.z = accA.z * invA + accB.z * invB;
  s4.w = accA.w * invA + accB.w * invB;
  s4.x += __shfl_xor(s4.x, 32);
  s4.y += __shfl_xor(s4.y, 32);
  s4.z += __shfl_xor(s4.z, 32);
  s4.w += __shfl_xor(s4.w, 32);
  int c0 = (4 * lane) & 127;
  float4 b2v = *(const float4*)(b2 + c0);
  s4.x = s4.x * 0.25f + b2v.x;
  s4.y = s4.y * 0.25f + b2v.y;
  s4.z = s4.z * 0.25f + b2v.z;
  s4.w = s4.w * 0.25f + b2v.w;
  float part = s4.x + s4.y + s4.z + s4.w;
  for (int m = 1; m < 32; m <<= 1) part += __shfl_xor(part, m);
  float mu = part * (1.f / 128.f);
  float dx = s4.x - mu, dy = s4.y - mu, dz = s4.z - mu, dw = s4.w - mu;
  float sq = dx * dx + dy * dy + dz * dz + dw * dw;
  for (int m = 1; m < 32; m <<= 1) sq += __shfl_xor(sq, m);
  float r = rsqrtf(sq * (1.f / 128.f) + 1e-5f);
  float4 g = *(const float4*)(gamma + c0);
  float4 bt = *(const float4*)(beta + c0);
  if (lane < 32) {
    float4 o;
    o.x = dx * r * g.x + bt.x;
    o.y = dy * r * g.y + bt.y;
    o.z = dz * r * g.z + bt.z;
    o.w = dw * r * g.w + bt.w;
    *(float4*)(out + (size_t)node * 128 + c0) = o;
  }
}

// ------------------------------- launcher ----------------------------------

extern "C" void kernel_launch(void* const* d_in, const int* in_sizes, int n_in,
                              void* d_out, int out_size, void* d_ws, size_t ws_size,
                              hipStream_t stream) {
  const float* x     = (const float*)d_in[0];
  const void*  ei    = d_in[1];
  const float* W1    = (const float*)d_in[2];
  const float* asrc1 = (const float*)d_in[3];
  const float* adst1 = (const float*)d_in[4];
  const float* b1    = (const float*)d_in[5];
  const float* W2    = (const float*)d_in[6];
  const float* asrc2 = (const float*)d_in[7];
  const float* adst2 = (const float*)d_in[8];
  const float* b2    = (const float*)d_in[9];
  const float* gamma = (const float*)d_in[10];
  const float* beta  = (const float*)d_in[11];
  float* out = (float*)d_out;

  const int E0 = in_sizes[1] / 2;       // 800000 raw edges
  const int ET = E0 + NNODES;           // + self loops

  // ws layout (<= ~84.1 MB, inside proven-safe bound). Lifetimes:
  //   h1  [0,25.6M)      gemm1 .. aggregate1
  //   h2  [0,51.2M)      gemm2 .. aggregate2      (after h1 dead)
  //   xb  [25.6M,38.4M)  convert .. gemm1
  //   Wt1 [38.4M,38.5M)  prep .. gemm1
  //   out1[51.2M,76.8M)  aggregate1 .. gemm2
  //   Wt2 [78.4M, +256K) prep .. gemm2   (es2 slot; es2 written after gemm2)
  char* w = (char*)d_ws;
  bf16_t* h1   = (bf16_t*)(w + 0);
  bf16_t* h2   = (bf16_t*)(w + 0);
  bf16_t* xb   = (bf16_t*)(w + 25600000);
  bf16_t* Wt1  = (bf16_t*)(w + 38400000);
  bf16_t* out1 = (bf16_t*)(w + 51200000);
  float* es1  = (float*)(w + 76800000);
  float* ed1  = (float*)(w + 77600000);
  float* es2  = (float*)(w + 78400000);
  bf16_t* Wt2  = (bf16_t*)(w + 78400000);   // dead before es2 written
  float* ed2  = (float*)(w + 79200000);
  int* rowptr = (int*)(w + 80000000);
  int* cursor = (int*)(w + 80200064);
  int* counts = (int*)(w + 80400128);
  int* col    = (int*)(w + 80600192);
  int* bsums  = (int*)(w + 84000192);
  int* boff   = (int*)(w + 84000448);
  int* mode   = (int*)(w + 84000704);

  const int NB = (NNODES + 1023) / 1024;   // 49

  // ---- prep: bf16 conversions ----
  convert_x_kernel<<<(NNODES * 128 / 4 + 255) / 256, 256, 0, stream>>>(x, xb,
                                                                       NNODES * 128 / 4);
  transpose_w_kernel<128, 256><<<256, 128, 0, stream>>>(W1, Wt1);
  transpose_w_kernel<256, 512><<<512, 256, 0, stream>>>(W2, Wt2);

  // ---- edge dtype detect + CSR build ----
  detect_kernel<<<1, 256, 0, stream>>>((const int*)ei, mode);
  zero_kernel<<<(NNODES + 255) / 256, 256, 0, stream>>>(counts, NNODES);
  hist_kernel<<<(ET + 255) / 256, 256, 0, stream>>>(ei, mode, counts, E0, ET);
  scan1_kernel<<<NB, 1024, 0, stream>>>(counts, rowptr, bsums);
  scan2_kernel<<<1, 64, 0, stream>>>(bsums, boff, NB, rowptr, cursor);
  scan3_kernel<<<NB, 1024, 0, stream>>>(boff, rowptr, cursor);
  fill_kernel<<<(ET + 255) / 256, 256, 0, stream>>>(ei, mode, cursor, col, E0, ET);

  const int MB = (NNODES + 63) / 64;       // 782
  const int NODE_BLOCKS = (NNODES + 3) / 4;

  // ---- layer 1 ----
  gemm_mfma_kernel<128, 256><<<dim3(MB, 4), 256, 0, stream>>>(xb, Wt1, h1, NNODES);
  scores1_kernel<<<NODE_BLOCKS, 256, 0, stream>>>(h1, asrc1, adst1, es1, ed1);
  aggregate1_kernel<<<NODE_BLOCKS, 256, 0, stream>>>(h1, es1, ed1, rowptr, col, b1, out1);

  // ---- layer 2 ----
  gemm_mfma_kernel<256, 512><<<dim3(MB, 8), 256, 0, stream>>>(out1, Wt2, h2, NNODES);
  scores2_kernel<<<NODE_BLOCKS, 256, 0, stream>>>(h2, asrc2, adst2, es2, ed2);
  aggregate2_ln_kernel<<<NODE_BLOCKS, 256, 0, stream>>>(h2, es2, ed2, rowptr, col,
                                                        b2, gamma, beta, out);
}